// Round 9
// baseline (293.601 us; speedup 1.0000x reference)
//
#include <hip/hip_runtime.h>
#include <hip/hip_bf16.h>
#include <math.h>

// Problem constants (B=4, T=2048, C=1024, H=16, D=64)
#define SEQ   2048
#define NTOK  8192          // B*T
#define EMB   1024
#define QKVF  3072
#define QSCALE 0.18033688f  // 0.125 * log2(e): folded into q-projection

typedef __bf16 bf16;
typedef __bf16 bf16x8 __attribute__((ext_vector_type(8)));
typedef __bf16 bf16x4 __attribute__((ext_vector_type(4)));
typedef unsigned short u16x8 __attribute__((ext_vector_type(8)));
typedef float  f32x4  __attribute__((ext_vector_type(4)));

__device__ __forceinline__ void gload_lds16(const bf16* g, bf16* l) {
    __builtin_amdgcn_global_load_lds(
        (const __attribute__((address_space(1))) unsigned int*)g,
        (__attribute__((address_space(3))) unsigned int*)l,
        16, 0, 0);
}

// ---------------- fp32 -> bf16 conversion (vectorized x4) ----------------
__global__ __launch_bounds__(256) void cvt_f32_bf16(const float* __restrict__ in,
                                                    bf16* __restrict__ out, int n) {
    int i = (blockIdx.x * 256 + threadIdx.x) * 4;
    if (i >= n) return;
    float4 f = *reinterpret_cast<const float4*>(in + i);
    bf16x4 o;
    o[0] = (bf16)f.x; o[1] = (bf16)f.y; o[2] = (bf16)f.z; o[3] = (bf16)f.w;
    *reinterpret_cast<bf16x4*>(out + i) = o;
}

// qkv_w conversion with q-rows (first EMB*EMB elements) pre-scaled by QSCALE
__global__ __launch_bounds__(256) void cvt_qkvw_bf16(const float* __restrict__ in,
                                                     bf16* __restrict__ out) {
    int i = (blockIdx.x * 256 + threadIdx.x) * 4;
    float4 f = *reinterpret_cast<const float4*>(in + i);
    const float s = (i < EMB * EMB) ? QSCALE : 1.f;
    bf16x4 o;
    o[0] = (bf16)(f.x * s); o[1] = (bf16)(f.y * s);
    o[2] = (bf16)(f.z * s); o[3] = (bf16)(f.w * s);
    *reinterpret_cast<bf16x4*>(out + i) = o;
}

// ---------------- 8-wave bt-GEMM: C[M,N] = A[M,K]*B[N,K]^T + bias ----------
// (FROZEN from R7 for attribution) BM=WR*64, BN=WC*64, BK=64, 512 threads.
// 2-phase double-buffer + counted vmcnt; T2 XOR swizzle.
template <int WR, int WC, bool BF16OUT>
__global__ __launch_bounds__(512, 2) void gemm_bt8(const bf16* __restrict__ A,
                                                   const bf16* __restrict__ Bm,
                                                   const float* __restrict__ bias,
                                                   void* __restrict__ out,
                                                   int M, int N, int K, int scale_cols) {
    constexpr int BM = WR * 64, BN = WC * 64;
    constexpr int WN = WR + WC;           // loads/thread/K-step (= counted vmcnt)
    __shared__ bf16 As[2][BM * 64];
    __shared__ bf16 Bs[2][BN * 64];

    const int nbx = N / BN;
    const int q8  = (nbx * (M / BM)) >> 3;
    const int swz = ((int)blockIdx.x & 7) * q8 + ((int)blockIdx.x >> 3);
    const int bx  = swz % nbx;
    const int by  = swz / nbx;

    const int tid  = threadIdx.x;
    const int lane = tid & 63;
    const int wid  = tid >> 6;
    const int wr   = wid / WC, wc = wid % WC;
    const int lr   = lane & 15, hi = lane >> 4;
    const size_t brow = (size_t)by * BM;
    const size_t bcol = (size_t)bx * BN;

    const f32x4 fzero = {0.f, 0.f, 0.f, 0.f};
    f32x4 acc[4][4];
#pragma unroll
    for (int m = 0; m < 4; ++m)
#pragma unroll
        for (int n = 0; n < 4; ++n) acc[m][n] = fzero;

    const int r8 = tid >> 3;      // staging row-within-round (0..63)
    const int c8 = tid & 7;       // staging 16B-chunk

#define STAGE(buf, kt) do {                                                     \
    _Pragma("unroll")                                                           \
    for (int i_ = 0; i_ < WR; ++i_) {                                           \
        const int row_ = i_ * 64 + r8;                                          \
        const int cg_  = c8 ^ (row_ & 7);                                       \
        gload_lds16(A + (brow + row_) * (size_t)K + (size_t)(kt) * 64 + cg_*8,  \
                    &As[buf][i_ * 4096 + tid * 8]);                             \
    }                                                                           \
    _Pragma("unroll")                                                           \
    for (int i_ = 0; i_ < WC; ++i_) {                                           \
        const int row_ = i_ * 64 + r8;                                          \
        const int cg_  = c8 ^ (row_ & 7);                                       \
        gload_lds16(Bm + (bcol + row_) * (size_t)K + (size_t)(kt) * 64 + cg_*8, \
                    &Bs[buf][i_ * 4096 + tid * 8]);                             \
    }                                                                           \
} while (0)

    const int NT = K >> 6;
    STAGE(0, 0);                  // WN loads in flight
    int cur = 0;

    for (int kt = 0; kt < NT; ++kt) {
        if (kt + 1 < NT) {
            STAGE(cur ^ 1, kt + 1);                              // +WN in flight
            asm volatile("s_waitcnt vmcnt(%0)" :: "i"(WN) : "memory"); // buf[cur] landed
        } else {
            asm volatile("s_waitcnt vmcnt(0)" ::: "memory");
        }
        __builtin_amdgcn_s_barrier();    // all waves' buf[cur] staged

#pragma unroll
        for (int kk = 0; kk < 2; ++kk) {
            bf16x8 af[4], bfr[4];
#pragma unroll
            for (int m = 0; m < 4; ++m) {
                const int row = wr * 64 + m * 16 + lr;
                af[m] = *reinterpret_cast<const bf16x8*>(
                    (const char*)&As[cur][0] + row * 128 +
                    ((kk * 64 + hi * 16) ^ ((row & 7) << 4)));
            }
#pragma unroll
            for (int n = 0; n < 4; ++n) {
                const int row = wc * 64 + n * 16 + lr;
                bfr[n] = *reinterpret_cast<const bf16x8*>(
                    (const char*)&Bs[cur][0] + row * 128 +
                    ((kk * 64 + hi * 16) ^ ((row & 7) << 4)));
            }
            __builtin_amdgcn_s_setprio(1);
#pragma unroll
            for (int m = 0; m < 4; ++m)
#pragma unroll
                for (int n = 0; n < 4; ++n)
                    acc[m][n] = __builtin_amdgcn_mfma_f32_16x16x32_bf16(
                        af[m], bfr[n], acc[m][n], 0, 0, 0);
            __builtin_amdgcn_s_setprio(0);
        }

        asm volatile("s_waitcnt lgkmcnt(0)" ::: "memory");  // my reads of buf[cur] done
        __builtin_amdgcn_s_barrier();                       // everyone's reads done
        cur ^= 1;
    }

#pragma unroll
    for (int m = 0; m < 4; ++m)
#pragma unroll
        for (int n = 0; n < 4; ++n)
#pragma unroll
            for (int r = 0; r < 4; ++r) {
                const size_t row = brow + wr * 64 + m * 16 + hi * 4 + r;
                const size_t col = bcol + wc * 64 + n * 16 + lr;
                const float bb = bias[col];
                const float v = acc[m][n][r] + (((int)col < scale_cols) ? bb * QSCALE : bb);
                if (BF16OUT)
                    ((bf16*)out)[row * (size_t)N + col] = (bf16)v;
                else
                    ((float*)out)[row * (size_t)N + col] = v;
            }
#undef STAGE
}

// ---------------- causal flash attention (pipelined staging) ----------------
// 128 q-rows/block, 4 waves (32 each), KV tiles of 64.
// K double-buffered via gload_lds issued mid-iteration; V prefetched to
// REGISTERS during compute(t) and scattered at top of t+1 (T14). Single
// vmcnt(0) per iteration, one compute-phase of latency cover. Defer-max.
__global__ __launch_bounds__(256, 4) void attn_kernel(const bf16* __restrict__ qkv,
                                                      bf16* __restrict__ o) {
    const int bid = blockIdx.x;
    const int qt  = 15 - (bid >> 6);     // 16 q-tiles; longest first
    const int bh  = bid & 63;
    const int h   = bh & 15;
    const int b   = bh >> 4;
    const int qbase = qt * 128;

    const int tid  = threadIdx.x;
    const int wv   = tid >> 6;
    const int lane = tid & 63;
    const int lr   = lane & 15, hi = lane >> 4;

    __shared__ bf16 Ks[2][64 * 64];       // K tile [k][d], XOR-swizzled rows (dbuf)
    __shared__ bf16 Vt[64 * 64];          // V^T tile [d][k], XOR-swizzled rows
    __shared__ bf16 Pl[4 * 32 * 64];      // per-wave P [q][k], XOR-swizzled rows

    char* Vtb = (char*)Vt;
    char* Pb  = (char*)(Pl + wv * 2048);

    const size_t tokbase = (size_t)b * SEQ;

    // Hoist Q (B-operand of swapped QK^T); Q already carries 0.125*log2e
    bf16x8 aq[2][2];
#pragma unroll
    for (int qf = 0; qf < 2; ++qf) {
        const bf16* qg = qkv + (tokbase + qbase + wv * 32 + qf * 16 + lr) * (size_t)QKVF
                         + h * 64;
#pragma unroll
        for (int kk = 0; kk < 2; ++kk)
            aq[qf][kk] = *reinterpret_cast<const bf16x8*>(qg + kk * 32 + hi * 8);
    }

    const f32x4 fzero = {0.f, 0.f, 0.f, 0.f};
    f32x4 oacc[2][4];
#pragma unroll
    for (int qf = 0; qf < 2; ++qf)
#pragma unroll
        for (int n = 0; n < 4; ++n) oacc[qf][n] = fzero;
    float m_r[2] = {-__builtin_inff(), -__builtin_inff()};
    float l_r[2] = {0.f, 0.f};

    const int nkv = qt * 2 + 2;

    const int kp = tid >> 3;              // V staging: k-pair index (k = 2kp, 2kp+1)
    const int vc = tid & 7;               // V staging: 16B d-chunk
    const int kr8 = lane >> 3;            // K staging helpers
    const int kc8 = (lane & 7) ^ ((lane >> 3) & 7);

#define STAGE_K(dst, kvrow) do {                                                 \
    _Pragma("unroll")                                                            \
    for (int j_ = 0; j_ < 2; ++j_) {                                             \
        const int kr_ = wv * 16 + j_ * 8 + kr8;                                  \
        gload_lds16(qkv + ((kvrow) + kr_) * (size_t)QKVF + EMB + h * 64 + kc8*8, \
                    &(dst)[(wv * 16 + j_ * 8) * 64 + lane * 8]);                 \
    }                                                                            \
} while (0)
#define LOAD_V(kvrow, v0_, v1_) do {                                             \
    const bf16* vg_ = qkv + ((kvrow) + 2 * kp) * (size_t)QKVF + 2 * EMB + h * 64 \
                      + vc * 8;                                                  \
    v0_ = *reinterpret_cast<const u16x8*>(vg_);                                  \
    v1_ = *reinterpret_cast<const u16x8*>(vg_ + QKVF);                           \
} while (0)

    // prologue: K(0) -> Ks[0], V(0) -> regs
    STAGE_K(Ks[0], tokbase);
    u16x8 nv0, nv1;
    LOAD_V(tokbase, nv0, nv1);

    for (int kt = 0; kt < nkv; ++kt) {
        const char* Ksb = (const char*)Ks[kt & 1];

        // (a) all in-flight staging (K(kt) LDS + V(kt) regs) landed; all waves
        // done reading Vt(kt-1)/Ks[(kt)&1 from two iters ago]
        __syncthreads();   // emits s_waitcnt vmcnt(0) lgkmcnt(0); s_barrier

        // scatter V(kt) regs -> Vt (adjacent k-pair packed b32 writes)
#pragma unroll
        for (int jj = 0; jj < 8; ++jj) {
            const int d = vc * 8 + jj;
            const unsigned int pr = (unsigned int)nv0[jj] | ((unsigned int)nv1[jj] << 16);
            *(unsigned int*)(Vtb + d * 128 + ((4 * kp) ^ (vc << 4))) = pr;
        }

        // issue K(kt+1) into the other LDS buffer (landing checked next iter)
        if (kt + 1 < nkv)
            STAGE_K(Ks[(kt + 1) & 1], tokbase + (size_t)(kt + 1) * 64);

        // (b) V-scatter visible to all waves; do NOT drain vmcnt here
        asm volatile("s_waitcnt lgkmcnt(0)" ::: "memory");
        __builtin_amdgcn_s_barrier();
        __builtin_amdgcn_sched_barrier(0);

        // prefetch V(kt+1) to regs; latency hides under the compute below
        if (kt + 1 < nkv)
            LOAD_V(tokbase + (size_t)(kt + 1) * 64, nv0, nv1);

        // --- S^T = K Q^T : lane holds S[q=qf*16+lr][k=ktile*16+hi*4+r]
        f32x4 s[2][4];
#pragma unroll
        for (int qf = 0; qf < 2; ++qf)
#pragma unroll
            for (int ktile = 0; ktile < 4; ++ktile) s[qf][ktile] = fzero;
#pragma unroll
        for (int ktile = 0; ktile < 4; ++ktile)
#pragma unroll
            for (int kk = 0; kk < 2; ++kk) {
                const int kr = ktile * 16 + lr;
                bf16x8 ak = *reinterpret_cast<const bf16x8*>(
                    Ksb + kr * 128 + ((kk * 64 + hi * 16) ^ ((kr & 7) << 4)));
#pragma unroll
                for (int qf = 0; qf < 2; ++qf)
                    s[qf][ktile] = __builtin_amdgcn_mfma_f32_16x16x32_bf16(
                        ak, aq[qf][kk], s[qf][ktile], 0, 0, 0);
            }

        // --- causal mask: only on diagonal tiles (wave-uniform branch)
#pragma unroll
        for (int qf = 0; qf < 2; ++qf) {
            if (kt * 64 + 63 > qbase + wv * 32 + qf * 16) {
                const int qglob = qbase + wv * 32 + qf * 16 + lr;
#pragma unroll
                for (int ktile = 0; ktile < 4; ++ktile) {
                    const int kg0 = kt * 64 + ktile * 16 + hi * 4;
#pragma unroll
                    for (int r = 0; r < 4; ++r)
                        if (kg0 + r > qglob) s[qf][ktile][r] = -__builtin_inff();
                }
            }
        }

        // --- online softmax (tree reductions; defer-max skips rescale)
#pragma unroll
        for (int qf = 0; qf < 2; ++qf) {
            float t4[4];
#pragma unroll
            for (int ktile = 0; ktile < 4; ++ktile)
                t4[ktile] = fmaxf(fmaxf(s[qf][ktile][0], s[qf][ktile][1]),
                                  fmaxf(s[qf][ktile][2], s[qf][ktile][3]));
            float tm = fmaxf(fmaxf(t4[0], t4[1]), fmaxf(t4[2], t4[3]));
            tm = fmaxf(tm, __shfl_xor(tm, 16));
            tm = fmaxf(tm, __shfl_xor(tm, 32));

            const bool defer = __all(tm <= m_r[qf]);
            const float mn = defer ? m_r[qf] : fmaxf(m_r[qf], tm);

            float s4[4];
#pragma unroll
            for (int ktile = 0; ktile < 4; ++ktile) {
                float p0 = __builtin_amdgcn_exp2f(s[qf][ktile][0] - mn);
                float p1 = __builtin_amdgcn_exp2f(s[qf][ktile][1] - mn);
                float p2 = __builtin_amdgcn_exp2f(s[qf][ktile][2] - mn);
                float p3 = __builtin_amdgcn_exp2f(s[qf][ktile][3] - mn);
                s[qf][ktile][0] = p0; s[qf][ktile][1] = p1;
                s[qf][ktile][2] = p2; s[qf][ktile][3] = p3;
                s4[ktile] = (p0 + p1) + (p2 + p3);
            }
            float ts = (s4[0] + s4[1]) + (s4[2] + s4[3]);
            ts += __shfl_xor(ts, 16);
            ts += __shfl_xor(ts, 32);

            if (defer) {
                l_r[qf] += ts;
            } else {
                const float sc = __builtin_amdgcn_exp2f(m_r[qf] - mn);
                m_r[qf] = mn;
                l_r[qf] = l_r[qf] * sc + ts;
                float scb[4];
#pragma unroll
                for (int r = 0; r < 4; ++r) scb[r] = __shfl(sc, hi * 4 + r);
#pragma unroll
                for (int n = 0; n < 4; ++n)
#pragma unroll
                    for (int r = 0; r < 4; ++r) oacc[qf][n][r] *= scb[r];
            }

            // write P (bf16) to wave-private LDS, swizzled rows
            const int q = qf * 16 + lr;
#pragma unroll
            for (int ktile = 0; ktile < 4; ++ktile) {
                bf16x4 p4;
#pragma unroll
                for (int r = 0; r < 4; ++r) p4[r] = (bf16)s[qf][ktile][r];
                *(bf16x4*)(Pb + q * 128 + ((ktile * 32 + hi * 8) ^ ((q & 7) << 4))) = p4;
            }
        }

        // --- PV: O += P V
#pragma unroll
        for (int kk = 0; kk < 2; ++kk) {
            bf16x8 ap[2];
#pragma unroll
            for (int qf = 0; qf < 2; ++qf) {
                const int q = qf * 16 + lr;
                ap[qf] = *reinterpret_cast<const bf16x8*>(
                    Pb + q * 128 + ((kk * 64 + hi * 16) ^ ((q & 7) << 4)));
            }
#pragma unroll
            for (int n = 0; n < 4; ++n) {
                const int d = n * 16 + lr;
                bf16x8 bv = *reinterpret_cast<const bf16x8*>(
                    Vtb + d * 128 + ((kk * 64 + hi * 16) ^ (((d >> 3) & 7) << 4)));
#pragma unroll
                for (int qf = 0; qf < 2; ++qf)
                    oacc[qf][n] = __builtin_amdgcn_mfma_f32_16x16x32_bf16(
                        ap[qf], bv, oacc[qf][n], 0, 0, 0);
            }
        }
    }

    // --- epilogue: normalize and store
#pragma unroll
    for (int qf = 0; qf < 2; ++qf) {
        const float linv = 1.f / l_r[qf];
        float li[4];
#pragma unroll
        for (int r = 0; r < 4; ++r) li[r] = __shfl(linv, hi * 4 + r);
        bf16* og = o + (tokbase + qbase + wv * 32 + qf * 16) * (size_t)EMB + h * 64;
#pragma unroll
        for (int n = 0; n < 4; ++n)
#pragma unroll
            for (int r = 0; r < 4; ++r)
                og[(hi * 4 + r) * (size_t)EMB + n * 16 + lr] =
                    (bf16)(oacc[qf][n][r] * li[r]);
    }
#undef STAGE_K
#undef LOAD_V
}

// ---------------- launcher ----------------
extern "C" void kernel_launch(void* const* d_in, const int* in_sizes, int n_in,
                              void* d_out, int out_size, void* d_ws, size_t ws_size,
                              hipStream_t stream) {
    const float* x     = (const float*)d_in[0];
    const float* qkv_w = (const float*)d_in[1];
    const float* qkv_b = (const float*)d_in[2];
    const float* out_w = (const float*)d_in[3];
    const float* out_b = (const float*)d_in[4];
    float* out = (float*)d_out;

    char* ws = (char*)d_ws;
    bf16* x_bf    = (bf16*)(ws);                                  // 16 MB
    bf16* qkvw_bf = (bf16*)(ws + 16777216);                       //  6 MB
    bf16* outw_bf = (bf16*)(ws + 23068672);                       //  2 MB
    bf16* qkv_bf  = (bf16*)(ws + 25165824);                       // 48 MB
    bf16* o_bf    = (bf16*)(ws + 75497472);                       // 16 MB

    cvt_f32_bf16<<<8192, 256, 0, stream>>>(x,     x_bf,    NTOK * EMB);
    cvt_qkvw_bf16<<<3072, 256, 0, stream>>>(qkv_w, qkvw_bf);
    cvt_f32_bf16<<<1024, 256, 0, stream>>>(out_w, outw_bf, EMB * EMB);

    // QKV projection: BM=128, BN=256 -> grid 768 (frozen)
    gemm_bt8<2, 4, true><<<(NTOK / 128) * (QKVF / 256), 512, 0, stream>>>(
        x_bf, qkvw_bf, qkv_b, qkv_bf, NTOK, QKVF, EMB, EMB);

    // causal attention -> bf16 [8192,1024]; 128-row q-tiles, grid 1024
    attn_kernel<<<4 * 16 * (SEQ / 128), 256, 0, stream>>>(qkv_bf, o_bf);

    // output projection: BM=256, BN=128 -> grid 256 (frozen)
    gemm_bt8<4, 2, false><<<(NTOK / 256) * (EMB / 128), 512, 0, stream>>>(
        o_bf, outw_bf, out_b, out, NTOK, EMB, EMB, 0);
}